// Round 1
// baseline (307.021 us; speedup 1.0000x reference)
//
#include <hip/hip_runtime.h>
#include <math.h>

// Problem constants
#define DIM 64
#define KCB 512
#define NWIN 524288              // 16384 * 32 windows
#define ZQN (NWIN * DIM)         // 33554432
#define WPT 512                  // windows per tile
#define TPB 2                    // tiles per block
#define THREADS 1024             // 16 waves/block, 2 blocks/CU -> 32 waves/CU
#define NBLK (NWIN / (WPT * TPB))  // 512 blocks

typedef __attribute__((ext_vector_type(8))) short bf16x8;  // 8 bf16 = 4 VGPRs
typedef __attribute__((ext_vector_type(4))) float f32x4;

__device__ __forceinline__ unsigned bfbits(float f) { return __float_as_uint(f) >> 16; }

// pack 8 fp32 -> 8 bf16 (truncation; tolerance budget is enormous)
__device__ __forceinline__ int4 pack8(float4 a, float4 b) {
    int4 r;
    r.x = (int)(bfbits(a.x) | (__float_as_uint(a.y) & 0xffff0000u));
    r.y = (int)(bfbits(a.z) | (__float_as_uint(a.w) & 0xffff0000u));
    r.z = (int)(bfbits(b.x) | (__float_as_uint(b.y) & 0xffff0000u));
    r.w = (int)(bfbits(b.z) | (__float_as_uint(b.w) & 0xffff0000u));
    return r;
}

// ---------------------------------------------------------------------------
// Fused VQ kernel, v4 (occupancy push):
//  - 1024-thread blocks, __launch_bounds__(1024, 8): 2 blocks/CU at 72 KB LDS
//    -> 32 waves/CU (was 16). Requires <=64 VGPR, hence per-wave tile halved
//    (tt = 2 window-rows of 16) and no A-prefetch buffer (TLP covers it).
//  - all 512 codes staged once as bf16 MFMA B-frags (64 KiB LDS)
//  - score = 0.5||c||^2 - <z,c> entirely in MFMA: A holds -z, C-operand
//    initialized to halved code norm (broadcast)
//  - epilogue: v_and_or_b32 idx-pack into low 9 mantissa bits + v_min3_f32
//  - zq gather now reads codebook float4 from GLOBAL (L2-hot 128 KB):
//    no LDS bank conflicts, fewer VALU bit-ops, exact fp32 output.
//    zq stores nontemporal (pure streaming output).
// MFMA 16x16x32 bf16: A[m=lane&15][k=quad*8+j], B[k][n=lane&15],
// D: col(n)=lane&15, row(m)=quad*4+reg.
// ---------------------------------------------------------------------------
__global__ __launch_bounds__(THREADS, 8) void vq_fused_kernel(
    const float* __restrict__ ze, const float* __restrict__ cb,
    float* __restrict__ out_idx, float* __restrict__ zq,
    int* __restrict__ counts, float* __restrict__ lossAcc)
{
    __shared__ int4  bfr[4096];       // 64 KiB: B frags [chunk32][h2][lane64]
    __shared__ float norm_s[KCB];     // 2 KiB HALVED row norms (0.5*||c||^2)
    __shared__ int   idx_s[TPB][WPT]; // 4 KiB per-window argmin, double-buffered
    __shared__ int   hist_s[KCB];     // 2 KiB histogram
    __shared__ float lpart[16];

    const int t    = threadIdx.x;     // 0..1023
    const int lane = t & 63;
    const int wv   = t >> 6;          // wave 0..15
    const int q    = lane >> 4;
    const int l15  = lane & 15;
    const long blk = blockIdx.x;

    // ---- halved codebook row norms + histogram init (one row per thread)
    if (t < KCB) {
        hist_s[t] = 0;
        const float4* c4 = (const float4*)cb;
        float s = 0.f;
#pragma unroll
        for (int i = 0; i < 16; ++i) {
            float4 v = c4[t * 16 + i];
            s += v.x * v.x + v.y * v.y + v.z * v.z + v.w * v.w;
        }
        norm_s[t] = 0.5f * s;
    }

    // ---- stage ALL 512 codes as B fragments (once per block)
#pragma unroll
    for (int i = 0; i < 4; ++i) {
        int f = i * THREADS + t;
        int L = f & 63, rest = f >> 6, h = rest & 1, c = rest >> 1;  // c=0..31
        int n = c * 16 + (L & 15);
        int k = h * 32 + (L >> 4) * 8;
        const float4* s4 = (const float4*)(cb + n * DIM + k);
        bfr[(c * 2 + h) * 64 + L] = pack8(s4[0], s4[1]);
    }

    const float4* z4b = (const float4*)ze;
    const float4* c4g = (const float4*)cb;
    float4*       zq4 = (float4*)zq;
    float lsum = 0.f;

    __syncthreads();   // bfr + norms visible

#pragma unroll
    for (int tl = 0; tl < TPB; ++tl) {
        const long g = blk * TPB + tl;
        const float4* z4 = z4b + g * (long)(WPT * 16);
        const int m = wv * 32 + l15;   // + tt*16 below

        // ---- load + pack A to NEGATED bf16 frags + window norms
        bf16x8 afrag[2][2];
        float  znorm[2];
#pragma unroll
        for (int tt = 0; tt < 2; ++tt) {
            float part = 0.f;
#pragma unroll
            for (int h = 0; h < 2; ++h) {
                float4 a0 = z4[(m + tt * 16) * 16 + h * 8 + q * 2 + 0];
                float4 a1 = z4[(m + tt * 16) * 16 + h * 8 + q * 2 + 1];
                part += a0.x*a0.x + a0.y*a0.y + a0.z*a0.z + a0.w*a0.w
                      + a1.x*a1.x + a1.y*a1.y + a1.z*a1.z + a1.w*a1.w;
                int4 p = pack8(a0, a1);
                p.x ^= 0x80008000; p.y ^= 0x80008000;   // negate both bf16 halves
                p.z ^= 0x80008000; p.w ^= 0x80008000;
                afrag[tt][h] = __builtin_bit_cast(bf16x8, p);
            }
            part += __shfl_xor(part, 16, 64);
            part += __shfl_xor(part, 32, 64);
            znorm[tt] = part;
        }

        float best[2][4];
#pragma unroll
        for (int tt = 0; tt < 2; ++tt)
#pragma unroll
            for (int r = 0; r < 4; ++r) best[tt][r] = __uint_as_float(0x7e000000u);

        // ---- MFMA scan over 512 codes, 2 code-chunks per iteration
        for (int cp = 0; cp < 16; ++cp) {
            f32x4 e0[2], e1[2];
            {   // chunk c = 2*cp
                const int c = 2 * cp;
                bf16x8 b0 = __builtin_bit_cast(bf16x8, bfr[(c * 2 + 0) * 64 + lane]);
                bf16x8 b1 = __builtin_bit_cast(bf16x8, bfr[(c * 2 + 1) * 64 + lane]);
                float nh = norm_s[c * 16 + l15];
                f32x4 nrm4 = {nh, nh, nh, nh};
#pragma unroll
                for (int tt = 0; tt < 2; ++tt) {
                    e0[tt] = __builtin_amdgcn_mfma_f32_16x16x32_bf16(afrag[tt][0], b0, nrm4, 0, 0, 0);
                    e0[tt] = __builtin_amdgcn_mfma_f32_16x16x32_bf16(afrag[tt][1], b1, e0[tt], 0, 0, 0);
                }
            }
            {   // chunk c = 2*cp+1
                const int c = 2 * cp + 1;
                bf16x8 b0 = __builtin_bit_cast(bf16x8, bfr[(c * 2 + 0) * 64 + lane]);
                bf16x8 b1 = __builtin_bit_cast(bf16x8, bfr[(c * 2 + 1) * 64 + lane]);
                float nh = norm_s[c * 16 + l15];
                f32x4 nrm4 = {nh, nh, nh, nh};
#pragma unroll
                for (int tt = 0; tt < 2; ++tt) {
                    e1[tt] = __builtin_amdgcn_mfma_f32_16x16x32_bf16(afrag[tt][0], b0, nrm4, 0, 0, 0);
                    e1[tt] = __builtin_amdgcn_mfma_f32_16x16x32_bf16(afrag[tt][1], b1, e1[tt], 0, 0, 0);
                }
            }
            const unsigned n0 = (unsigned)(2 * cp) * 16 + (unsigned)l15;
            const unsigned n1 = n0 + 16;
#pragma unroll
            for (int tt = 0; tt < 2; ++tt)
#pragma unroll
                for (int r = 0; r < 4; ++r) {
                    float p0 = __uint_as_float((__float_as_uint(e0[tt][r]) & ~511u) | n0);
                    float p1 = __uint_as_float((__float_as_uint(e1[tt][r]) & ~511u) | n1);
                    best[tt][r] = fminf(fminf(best[tt][r], p0), p1);   // -> v_min3_f32
                }
        }

        // ---- min across the 16 lanes of each quad (n-direction)
#pragma unroll
        for (int tt = 0; tt < 2; ++tt)
#pragma unroll
            for (int r = 0; r < 4; ++r) {
                float v = best[tt][r];
                v = fminf(v, __shfl_xor(v, 1, 64));
                v = fminf(v, __shfl_xor(v, 2, 64));
                v = fminf(v, __shfl_xor(v, 4, 64));
                v = fminf(v, __shfl_xor(v, 8, 64));
                best[tt][r] = v;
            }

        // owner lanes (l15 == q*4+r) record idx + loss surrogate.
        // static r indexing (rule #20: no runtime-indexed register arrays)
#pragma unroll
        for (int r = 0; r < 4; ++r) {
            if (l15 == q * 4 + r) {
#pragma unroll
                for (int tt = 0; tt < 2; ++tt) {
                    unsigned bb = __float_as_uint(best[tt][r]);
                    int   n  = (int)(bb & 511u);
                    float sc = __uint_as_float(bb & ~511u);
                    lsum += fmaf(2.f, sc, znorm[tt]);      // d^2 = ||z||^2 + 2*score
                    idx_s[tl][wv * 32 + tt * 16 + l15] = n;
                }
            }
        }

        __syncthreads();   // idx_s[tl] complete

        // coalesced index write + local histogram (512 entries)
        if (t < WPT) {
            int n = idx_s[tl][t];
            out_idx[g * WPT + t] = (float)n;
            atomicAdd(&hist_s[n], 1);
        }

        // ---- zq gather straight from GLOBAL codebook (L2-hot, exact fp32)
        {
            const long zb = g * (long)(WPT * 16);   // float4 units
#pragma unroll
            for (int it = 0; it < 8; ++it) {
                int w_loc = it * 64 + (t >> 4);
                int j  = t & 15;            // float4 index in window
                int n  = idx_s[tl][w_loc];
                f32x4 o = *(const f32x4*)(c4g + n * 16 + j);
                __builtin_nontemporal_store(o, (f32x4*)(zq4 + zb + (long)w_loc * 16 + j));
            }
        }
        // no trailing barrier: next tile writes idx_s[tl^1], bfr/norm_s read-only
    }

    // ---- loss reduce + histogram flush
#pragma unroll
    for (int off = 32; off; off >>= 1) lsum += __shfl_down(lsum, off, 64);
    if (lane == 0) lpart[wv] = lsum;
    __syncthreads();   // also orders all hist_s atomics before the flush below
    if (t == 0) {
        float s = 0.f;
#pragma unroll
        for (int i = 0; i < 16; ++i) s += lpart[i];
        atomicAdd(lossAcc, s);
    }
    if (t < KCB) {
        int h0 = hist_s[t];
        if (h0) atomicAdd(&counts[t], h0);
    }
}

// ---------------------------------------------------------------------------
// Finalize: entropy from counts + loss scalars
// ---------------------------------------------------------------------------
__global__ __launch_bounds__(512) void vq_finalize_kernel(
    const int* __restrict__ counts, const float* __restrict__ lossAcc,
    float* __restrict__ outs)
{
    __shared__ float partial[8];
    const int t = threadIdx.x;

    float p = (float)counts[t] * 0.1f;
    float term = p * logf(p + 1e-10f);
#pragma unroll
    for (int off = 32; off; off >>= 1) term += __shfl_down(term, off, 64);
    if ((t & 63) == 0) partial[t >> 6] = term;
    __syncthreads();
    if (t == 0) {
        float e = 0.f;
#pragma unroll
        for (int i = 0; i < 8; ++i) e += partial[i];
        float loss = lossAcc[0] / (float)ZQN;
        outs[0] = loss;
        outs[1] = loss;
        outs[2] = e;
    }
}

extern "C" void kernel_launch(void* const* d_in, const int* in_sizes, int n_in,
                              void* d_out, int out_size, void* d_ws, size_t ws_size,
                              hipStream_t stream) {
    const float* ze = (const float*)d_in[0];   // [16384, 2048] fp32
    const float* cb = (const float*)d_in[1];   // [512, 64] fp32
    float* out = (float*)d_out;

    // d_out layout: [idx: NWIN | zq: ZQN | vq_e | vq_commit | entropy]
    float* out_idx = out;
    float* out_zq  = out + NWIN;
    float* out_scl = out + NWIN + (long)ZQN;

    int*   counts  = (int*)d_ws;
    float* lossAcc = (float*)((char*)d_ws + KCB * sizeof(int));
    hipMemsetAsync(d_ws, 0, KCB * sizeof(int) + sizeof(float), stream);

    vq_fused_kernel<<<NBLK, THREADS, 0, stream>>>(ze, cb, out_idx, out_zq, counts, lossAcc);
    vq_finalize_kernel<<<1, KCB, 0, stream>>>(counts, lossAcc, out_scl);
}

// Round 2
// 298.831 us; speedup vs baseline: 1.0274x; 1.0274x over previous
//
#include <hip/hip_runtime.h>
#include <math.h>

// Problem constants
#define DIM 64
#define KCB 512
#define NWIN 524288              // 16384 * 32 windows
#define ZQN (NWIN * DIM)         // 33554432
#define WPT 512                  // windows per tile
#define TPB 2                    // tiles per block
#define THREADS 1024             // 16 waves/block, 2 blocks/CU -> 32 waves/CU
#define NBLK (NWIN / (WPT * TPB))  // 512 blocks

typedef __attribute__((ext_vector_type(8))) short bf16x8;  // 8 bf16 = 4 VGPRs
typedef __attribute__((ext_vector_type(4))) float f32x4;

__device__ __forceinline__ unsigned bfbits(float f) { return __float_as_uint(f) >> 16; }

// pack 8 fp32 -> 8 bf16 (truncation; tolerance budget is enormous)
__device__ __forceinline__ int4 pack8(float4 a, float4 b) {
    int4 r;
    r.x = (int)(bfbits(a.x) | (__float_as_uint(a.y) & 0xffff0000u));
    r.y = (int)(bfbits(a.z) | (__float_as_uint(a.w) & 0xffff0000u));
    r.z = (int)(bfbits(b.x) | (__float_as_uint(b.y) & 0xffff0000u));
    r.w = (int)(bfbits(b.z) | (__float_as_uint(b.w) & 0xffff0000u));
    return r;
}

// ---------------------------------------------------------------------------
// Fused VQ kernel, v5 (v4 occupancy structure + v3 store path):
//  - 1024-thread blocks, __launch_bounds__(1024, 8): 2 blocks/CU at 74 KB LDS
//    -> 32 waves/CU. Per-wave tile tt=2, no A-prefetch (TLP covers latency).
//  - all 512 codes staged once as bf16 MFMA B-frags (64 KiB LDS)
//  - score = 0.5||c||^2 - <z,c> entirely in MFMA: A holds -z, C-operand
//    initialized to halved code norm (broadcast)
//  - epilogue: v_and_or_b32 idx-pack into low 9 mantissa bits + v_min3_f32
//  - zq gather BACK to LDS B-frags with PLAIN stores (v4's nontemporal/global
//    path added +165 MB HBM traffic: nt defeats L2 write-combine + L3
//    retention of ze; the LDS bank conflicts it avoided cost only ~3 us).
// MFMA 16x16x32 bf16: A[m=lane&15][k=quad*8+j], B[k][n=lane&15],
// D: col(n)=lane&15, row(m)=quad*4+reg.
// ---------------------------------------------------------------------------
__global__ __launch_bounds__(THREADS, 8) void vq_fused_kernel(
    const float* __restrict__ ze, const float* __restrict__ cb,
    float* __restrict__ out_idx, float* __restrict__ zq,
    int* __restrict__ counts, float* __restrict__ lossAcc)
{
    __shared__ int4  bfr[4096];       // 64 KiB: B frags [chunk32][h2][lane64]
    __shared__ float norm_s[KCB];     // 2 KiB HALVED row norms (0.5*||c||^2)
    __shared__ int   idx_s[TPB][WPT]; // 4 KiB per-window argmin, double-buffered
    __shared__ int   hist_s[KCB];     // 2 KiB histogram
    __shared__ float lpart[16];

    const int t    = threadIdx.x;     // 0..1023
    const int lane = t & 63;
    const int wv   = t >> 6;          // wave 0..15
    const int q    = lane >> 4;
    const int l15  = lane & 15;
    const long blk = blockIdx.x;

    // ---- halved codebook row norms + histogram init (one row per thread)
    if (t < KCB) {
        hist_s[t] = 0;
        const float4* c4 = (const float4*)cb;
        float s = 0.f;
#pragma unroll
        for (int i = 0; i < 16; ++i) {
            float4 v = c4[t * 16 + i];
            s += v.x * v.x + v.y * v.y + v.z * v.z + v.w * v.w;
        }
        norm_s[t] = 0.5f * s;
    }

    // ---- stage ALL 512 codes as B fragments (once per block)
#pragma unroll
    for (int i = 0; i < 4; ++i) {
        int f = i * THREADS + t;
        int L = f & 63, rest = f >> 6, h = rest & 1, c = rest >> 1;  // c=0..31
        int n = c * 16 + (L & 15);
        int k = h * 32 + (L >> 4) * 8;
        const float4* s4 = (const float4*)(cb + n * DIM + k);
        bfr[(c * 2 + h) * 64 + L] = pack8(s4[0], s4[1]);
    }

    const float4* z4b = (const float4*)ze;
    float4*       zq4 = (float4*)zq;
    float lsum = 0.f;

    __syncthreads();   // bfr + norms visible

#pragma unroll
    for (int tl = 0; tl < TPB; ++tl) {
        const long g = blk * TPB + tl;
        const float4* z4 = z4b + g * (long)(WPT * 16);
        const int m = wv * 32 + l15;   // + tt*16 below

        // ---- load + pack A to NEGATED bf16 frags + window norms
        bf16x8 afrag[2][2];
        float  znorm[2];
#pragma unroll
        for (int tt = 0; tt < 2; ++tt) {
            float part = 0.f;
#pragma unroll
            for (int h = 0; h < 2; ++h) {
                float4 a0 = z4[(m + tt * 16) * 16 + h * 8 + q * 2 + 0];
                float4 a1 = z4[(m + tt * 16) * 16 + h * 8 + q * 2 + 1];
                part += a0.x*a0.x + a0.y*a0.y + a0.z*a0.z + a0.w*a0.w
                      + a1.x*a1.x + a1.y*a1.y + a1.z*a1.z + a1.w*a1.w;
                int4 p = pack8(a0, a1);
                p.x ^= 0x80008000; p.y ^= 0x80008000;   // negate both bf16 halves
                p.z ^= 0x80008000; p.w ^= 0x80008000;
                afrag[tt][h] = __builtin_bit_cast(bf16x8, p);
            }
            part += __shfl_xor(part, 16, 64);
            part += __shfl_xor(part, 32, 64);
            znorm[tt] = part;
        }

        float best[2][4];
#pragma unroll
        for (int tt = 0; tt < 2; ++tt)
#pragma unroll
            for (int r = 0; r < 4; ++r) best[tt][r] = __uint_as_float(0x7e000000u);

        // ---- MFMA scan over 512 codes, 2 code-chunks per iteration
        for (int cp = 0; cp < 16; ++cp) {
            f32x4 e0[2], e1[2];
            {   // chunk c = 2*cp
                const int c = 2 * cp;
                bf16x8 b0 = __builtin_bit_cast(bf16x8, bfr[(c * 2 + 0) * 64 + lane]);
                bf16x8 b1 = __builtin_bit_cast(bf16x8, bfr[(c * 2 + 1) * 64 + lane]);
                float nh = norm_s[c * 16 + l15];
                f32x4 nrm4 = {nh, nh, nh, nh};
#pragma unroll
                for (int tt = 0; tt < 2; ++tt) {
                    e0[tt] = __builtin_amdgcn_mfma_f32_16x16x32_bf16(afrag[tt][0], b0, nrm4, 0, 0, 0);
                    e0[tt] = __builtin_amdgcn_mfma_f32_16x16x32_bf16(afrag[tt][1], b1, e0[tt], 0, 0, 0);
                }
            }
            {   // chunk c = 2*cp+1
                const int c = 2 * cp + 1;
                bf16x8 b0 = __builtin_bit_cast(bf16x8, bfr[(c * 2 + 0) * 64 + lane]);
                bf16x8 b1 = __builtin_bit_cast(bf16x8, bfr[(c * 2 + 1) * 64 + lane]);
                float nh = norm_s[c * 16 + l15];
                f32x4 nrm4 = {nh, nh, nh, nh};
#pragma unroll
                for (int tt = 0; tt < 2; ++tt) {
                    e1[tt] = __builtin_amdgcn_mfma_f32_16x16x32_bf16(afrag[tt][0], b0, nrm4, 0, 0, 0);
                    e1[tt] = __builtin_amdgcn_mfma_f32_16x16x32_bf16(afrag[tt][1], b1, e1[tt], 0, 0, 0);
                }
            }
            const unsigned n0 = (unsigned)(2 * cp) * 16 + (unsigned)l15;
            const unsigned n1 = n0 + 16;
#pragma unroll
            for (int tt = 0; tt < 2; ++tt)
#pragma unroll
                for (int r = 0; r < 4; ++r) {
                    float p0 = __uint_as_float((__float_as_uint(e0[tt][r]) & ~511u) | n0);
                    float p1 = __uint_as_float((__float_as_uint(e1[tt][r]) & ~511u) | n1);
                    best[tt][r] = fminf(fminf(best[tt][r], p0), p1);   // -> v_min3_f32
                }
        }

        // ---- min across the 16 lanes of each quad (n-direction)
#pragma unroll
        for (int tt = 0; tt < 2; ++tt)
#pragma unroll
            for (int r = 0; r < 4; ++r) {
                float v = best[tt][r];
                v = fminf(v, __shfl_xor(v, 1, 64));
                v = fminf(v, __shfl_xor(v, 2, 64));
                v = fminf(v, __shfl_xor(v, 4, 64));
                v = fminf(v, __shfl_xor(v, 8, 64));
                best[tt][r] = v;
            }

        // owner lanes (l15 == q*4+r) record idx + loss surrogate.
        // static r indexing (rule #20: no runtime-indexed register arrays)
#pragma unroll
        for (int r = 0; r < 4; ++r) {
            if (l15 == q * 4 + r) {
#pragma unroll
                for (int tt = 0; tt < 2; ++tt) {
                    unsigned bb = __float_as_uint(best[tt][r]);
                    int   n  = (int)(bb & 511u);
                    float sc = __uint_as_float(bb & ~511u);
                    lsum += fmaf(2.f, sc, znorm[tt]);      // d^2 = ||z||^2 + 2*score
                    idx_s[tl][wv * 32 + tt * 16 + l15] = n;
                }
            }
        }

        __syncthreads();   // idx_s[tl] complete

        // coalesced index write + local histogram (512 entries)
        if (t < WPT) {
            int n = idx_s[tl][t];
            out_idx[g * WPT + t] = (float)n;
            atomicAdd(&hist_s[n], 1);
        }

        // ---- zq gather straight from LDS frags (bf16 -> fp32), plain stores
        {
            const long zb = g * (long)(WPT * 16);   // float4 units
#pragma unroll
            for (int it = 0; it < 8; ++it) {
                int w_loc = it * 64 + (t >> 4);
                int j  = t & 15;            // float4 index in window
                int n  = idx_s[tl][w_loc];
                int c  = n >> 4, ln = n & 15;
                int h  = j >> 3;
                int q2 = (j >> 1) & 3;
                int4 v = bfr[(c * 2 + h) * 64 + q2 * 16 + ln];
                int a  = (j & 1) ? v.z : v.x;
                int b  = (j & 1) ? v.w : v.y;
                float4 o;
                o.x = __uint_as_float((unsigned)a << 16);
                o.y = __uint_as_float((unsigned)a & 0xffff0000u);
                o.z = __uint_as_float((unsigned)b << 16);
                o.w = __uint_as_float((unsigned)b & 0xffff0000u);
                zq4[zb + (long)w_loc * 16 + j] = o;
            }
        }
        // no trailing barrier: next tile writes idx_s[tl^1], bfr/norm_s read-only
    }

    // ---- loss reduce + histogram flush
#pragma unroll
    for (int off = 32; off; off >>= 1) lsum += __shfl_down(lsum, off, 64);
    if (lane == 0) lpart[wv] = lsum;
    __syncthreads();   // also orders all hist_s atomics before the flush below
    if (t == 0) {
        float s = 0.f;
#pragma unroll
        for (int i = 0; i < 16; ++i) s += lpart[i];
        atomicAdd(lossAcc, s);
    }
    if (t < KCB) {
        int h0 = hist_s[t];
        if (h0) atomicAdd(&counts[t], h0);
    }
}

// ---------------------------------------------------------------------------
// Finalize: entropy from counts + loss scalars
// ---------------------------------------------------------------------------
__global__ __launch_bounds__(512) void vq_finalize_kernel(
    const int* __restrict__ counts, const float* __restrict__ lossAcc,
    float* __restrict__ outs)
{
    __shared__ float partial[8];
    const int t = threadIdx.x;

    float p = (float)counts[t] * 0.1f;
    float term = p * logf(p + 1e-10f);
#pragma unroll
    for (int off = 32; off; off >>= 1) term += __shfl_down(term, off, 64);
    if ((t & 63) == 0) partial[t >> 6] = term;
    __syncthreads();
    if (t == 0) {
        float e = 0.f;
#pragma unroll
        for (int i = 0; i < 8; ++i) e += partial[i];
        float loss = lossAcc[0] / (float)ZQN;
        outs[0] = loss;
        outs[1] = loss;
        outs[2] = e;
    }
}

extern "C" void kernel_launch(void* const* d_in, const int* in_sizes, int n_in,
                              void* d_out, int out_size, void* d_ws, size_t ws_size,
                              hipStream_t stream) {
    const float* ze = (const float*)d_in[0];   // [16384, 2048] fp32
    const float* cb = (const float*)d_in[1];   // [512, 64] fp32
    float* out = (float*)d_out;

    // d_out layout: [idx: NWIN | zq: ZQN | vq_e | vq_commit | entropy]
    float* out_idx = out;
    float* out_zq  = out + NWIN;
    float* out_scl = out + NWIN + (long)ZQN;

    int*   counts  = (int*)d_ws;
    float* lossAcc = (float*)((char*)d_ws + KCB * sizeof(int));
    hipMemsetAsync(d_ws, 0, KCB * sizeof(int) + sizeof(float), stream);

    vq_fused_kernel<<<NBLK, THREADS, 0, stream>>>(ze, cb, out_idx, out_zq, counts, lossAcc);
    vq_finalize_kernel<<<1, KCB, 0, stream>>>(counts, lossAcc, out_scl);
}